// Round 1
// 63.179 us; speedup vs baseline: 1.1408x; 1.1408x over previous
//
#include <hip/hip_runtime.h>
#include <math.h>

#define NQ 10
#define BATCHN 8192

// ---------------------------------------------------------------------------
// Analytic collapse of the circuit (verified against hand-computed sub-cases):
//
// State after encoding + ZZ layer: |psi> = (1/32) sum_j e^{i phi_j} |j>,
//   phi(s) = -pi*sum_q x_q s_q + pi*sum_{c<t} x_c x_t s_c s_t   (s_q = +/-1).
// Observable: <psi| E R'E' Rf' (-Z0) Rf E R E |psi>. Heisenberg conjugation:
//   Rf'(-Z0)Rf = -cosB Z0 + sinB X0,            B = 2pi(w0+w1+w2)
//   E'(.)E     = -cosB Z0 + sinB X0X1
//   R'(.)R     = -cosB[ct0 Z0 + st0 cl0 Y0 + st0 sl0 X0]
//                + sinB (cl0 X0 - sl0 Y0)(cl1 X1 - sl1 Y1)
//   E'(.)E     = 7 Pauli strings on qubits {0,1,2} only.
// <Z0> = 0 (uniform magnitudes). For the rest, Delta(phi) is linear in the
// unflipped spins -> the 1024-term sums factorize into cosine products:
//
// result = -g0 * sum_{m in {x0+x1, x0-x1}} S(m+w13) * C(m*x2)     * K(m)
//          +g1 * sum_{n in {x0+x2, x0-x2}} C(n+w13) * C(n*x1-w14) * K(n)
// with S/C = sin/cos(2pi * .), K(m) = prod_{t=3..9} C(m*x_t),
//      g0 = 0.5*cos(2pi(w0+w1+w2))*sin(2pi*w3), g1 = 0.5*sin(2pi(w0+w1+w2)).
// (w[4..12] and w[15..22] provably do not affect the output.)
//
// ws layout: [0..63] int per-block any(in>1) flags; [64..67] float {g0,g1,l0,l1}
// ---------------------------------------------------------------------------

__global__ __launch_bounds__(256) void prep_kernel(const float* __restrict__ in,
                                                   int n,
                                                   const float* __restrict__ w,
                                                   int* __restrict__ flags,
                                                   float* __restrict__ gtab) {
    __shared__ int bf;
    if (threadIdx.x == 0) bf = 0;
    __syncthreads();
    const int tid = blockIdx.x * 256 + threadIdx.x;
    bool pred = false;
    for (int i = tid; i < n; i += 64 * 256) pred |= (in[i] > 1.0f);
    if (__any(pred) && (threadIdx.x & 63) == 0) atomicOr(&bf, 1);
    __syncthreads();
    if (threadIdx.x == 0) flags[blockIdx.x] = bf;

    if (blockIdx.x == 0 && threadIdx.x == 0) {
        const float sw  = w[0] + w[1] + w[2];           // beta / 2pi
        const float cb  = __builtin_amdgcn_cosf(sw);    // cos(2pi*sw)
        const float sb  = __builtin_amdgcn_sinf(sw);
        const float st0 = __builtin_amdgcn_sinf(w[3]);  // sin(2pi*w3)
        gtab[0] = 0.5f * cb * st0;   // g0
        gtab[1] = 0.5f * sb;         // g1
        gtab[2] = w[13];             // lambda0 / 2pi
        gtab[3] = w[14];             // lambda1 / 2pi
    }
}

__global__ __launch_bounds__(256) void expect_kernel(const float* __restrict__ in,
                                                     const int* __restrict__ flags,
                                                     const float* __restrict__ G,
                                                     float* __restrict__ out) {
    __shared__ float xs[256 * NQ];
    const int base = blockIdx.x * (256 * NQ);
    for (int i = threadIdx.x; i < 256 * NQ; i += 256) xs[i] = in[base + i];

    const int lane = threadIdx.x & 63;
    const bool anyflag = __any(flags[lane] != 0);

    const float g0 = G[0], g1 = G[1], l0 = G[2], l1 = G[3];

    __syncthreads();

    float x[NQ];
#pragma unroll
    for (int q = 0; q < NQ; ++q) x[q] = xs[threadIdx.x * NQ + q];
    if (anyflag) {
#pragma unroll
        for (int q = 0; q < NQ; ++q) x[q] = atanf(x[q]);
    }

    const float mp = x[0] + x[1], mm = x[0] - x[1];   // F={0,1} combos
    const float np_ = x[0] + x[2], nm = x[0] - x[2];  // F={0,2} combos

    float Kmp = 1.0f, Kmm = 1.0f, Knp = 1.0f, Knm = 1.0f;
#pragma unroll
    for (int t = 3; t < NQ; ++t) {
        Kmp *= __builtin_amdgcn_cosf(mp * x[t]);
        Kmm *= __builtin_amdgcn_cosf(mm * x[t]);
        Knp *= __builtin_amdgcn_cosf(np_ * x[t]);
        Knm *= __builtin_amdgcn_cosf(nm * x[t]);
    }

    const float t1 = __builtin_amdgcn_sinf(mp + l0) * __builtin_amdgcn_cosf(mp * x[2]) * Kmp
                   + __builtin_amdgcn_sinf(mm + l0) * __builtin_amdgcn_cosf(mm * x[2]) * Kmm;
    const float t2 = __builtin_amdgcn_cosf(np_ + l0) * __builtin_amdgcn_cosf(np_ * x[1] - l1) * Knp
                   + __builtin_amdgcn_cosf(nm + l0) * __builtin_amdgcn_cosf(nm * x[1] - l1) * Knm;

    const int b = blockIdx.x * 256 + threadIdx.x;
    out[b] = fmaf(-g0, t1, g1 * t2);
}

extern "C" void kernel_launch(void* const* d_in, const int* in_sizes, int n_in,
                              void* d_out, int out_size, void* d_ws, size_t ws_size,
                              hipStream_t stream) {
    const float* inputs = (const float*)d_in[0];   // (8192, 10) float32
    const float* weight = (const float*)d_in[1];   // (23,) float32
    // d_in[2] = entangle_matrix — folded analytically (Clifford conjugation), unused.
    float* out   = (float*)d_out;                  // (8192,) float32
    int*   flags = (int*)d_ws;                     // 64 ints
    float* gtab  = (float*)d_ws + 64;              // 4 floats

    prep_kernel<<<64, 256, 0, stream>>>(inputs, BATCHN * NQ, weight, flags, gtab);
    expect_kernel<<<BATCHN / 256, 256, 0, stream>>>(inputs, flags, gtab, out);
}